// Round 6
// baseline (874.660 us; speedup 1.0000x reference)
//
#include <hip/hip_runtime.h>
#include <hip/hip_bf16.h>
#include <math.h>

#define NEG_SLOPE 0.2f
#define LOG2E 1.4426950408889634f

using bf16x8 = __attribute__((ext_vector_type(8))) short;
using f32x4  = __attribute__((ext_vector_type(4))) float;
using u16x8  = __attribute__((ext_vector_type(8))) unsigned short;
using u16x4  = __attribute__((ext_vector_type(4))) unsigned short;

__device__ __forceinline__ float lrelu(float x) { return x > 0.f ? x : NEG_SLOPE * x; }
__device__ __forceinline__ unsigned short f2b(float x) {
    union { float f; unsigned u; } v; v.f = x;
    unsigned r = v.u + 0x7fff + ((v.u >> 16) & 1);
    return (unsigned short)(r >> 16);
}
__device__ __forceinline__ float b2f(unsigned short b) {
    union { unsigned u; float f; } v; v.u = ((unsigned)b) << 16;
    return v.f;
}

// ---------------------------------------------------------------------------
// Pack Wcat = [W1 | W2] (each 128x256 fp32, k-major) into MFMA B-fragment
// linear order, bf16. Batched: blockIdx.y selects the weight pair.
// ---------------------------------------------------------------------------
struct PackArgs {
    const float* W1[2];
    const float* W2[2];
    unsigned short* Bp[2];
};

__global__ __launch_bounds__(256)
void pack_b_k(PackArgs pa)
{
    const int p = blockIdx.y;
    const int gid = blockIdx.x * 256 + threadIdx.x;  // 0..8191
    const int lane = gid & 63;
    const int grp = gid >> 6;          // 0..127
    const int ks = grp & 3;
    const int nb = grp >> 2;           // 0..31
    const int n = nb * 16 + (lane & 15);
    const int k0 = ks * 32 + (lane >> 4) * 8;
    const float* Wsrc = (n < 256) ? (pa.W1[p] + n) : (pa.W2[p] + (n - 256));
    u16x8 u;
    #pragma unroll
    for (int e = 0; e < 8; ++e) u[e] = f2b(Wsrc[(size_t)(k0 + e) * 256]);
    *reinterpret_cast<u16x8*>(pa.Bp[p] + (size_t)gid * 8) = u;
}

// ---------------------------------------------------------------------------
// MFMA GEMM, batched over 4 tuples via blockIdx.y.
// A[N x 128] fp32 @ Wcat[128 x 512] bf16-frags -> pool (cols 0-255, bf16),
// resid (cols 256-511, +bres, bf16). Fused head scores (el/er) computed from
// the pool tile while it sits in LDS (saves a full pool re-read by a separate
// scores kernel). el/er are pre-scaled by LOG2E via wvec scaling in rel_k.
// ---------------------------------------------------------------------------
struct GemmArgs {
    const float* A[4];
    const unsigned short* Bp[4];
    const float* bres[4];
    unsigned short* pool[4];
    unsigned short* resid[4];
    const float* wvA[4];
    const float* wvB[4];
    float* elOut[4];
    float* erOut[4];
};

__global__ __launch_bounds__(512)
void mfma_gemm_k(GemmArgs ga, int Nrows)
{
    __shared__ __align__(16) char smem[65536];
    unsigned short* Asw = (unsigned short*)smem;
    const int rsel = blockIdx.y;
    const float* __restrict__ A = ga.A[rsel];
    const unsigned short* __restrict__ Bp = ga.Bp[rsel];
    const float* __restrict__ bres = ga.bres[rsel];
    const int t = threadIdx.x;
    const int m0 = blockIdx.x * 128;

    // stage A: 128 rows x 128 k, fp32 -> bf16, XOR-swizzled (first 32 KB)
    #pragma unroll
    for (int i = 0; i < 4; ++i) {
        const int idx = i * 512 + t;        // 0..2047
        const int row = idx >> 4;           // 0..127
        const int cg  = idx & 15;           // 16B chunk (8 bf16)
        float4 a0 = make_float4(0.f, 0.f, 0.f, 0.f), a1 = a0;
        if (m0 + row < Nrows) {
            const float* p = A + (size_t)(m0 + row) * 128 + cg * 8;
            a0 = *reinterpret_cast<const float4*>(p);
            a1 = *reinterpret_cast<const float4*>(p + 4);
        }
        u16x8 u;
        u[0] = f2b(a0.x); u[1] = f2b(a0.y); u[2] = f2b(a0.z); u[3] = f2b(a0.w);
        u[4] = f2b(a1.x); u[5] = f2b(a1.y); u[6] = f2b(a1.z); u[7] = f2b(a1.w);
        const int off = row * 256 + ((cg * 16) ^ ((row & 7) << 4));
        *reinterpret_cast<u16x8*>((char*)Asw + off) = u;
    }
    __syncthreads();

    const int wv = t >> 6, lane = t & 63;
    const int mh = wv >> 2;          // row half (0/1)
    const int wn = wv & 3;           // 128-col slice
    const int l15 = lane & 15, lg = lane >> 4;
    const int nbb = wn * 8;

    f32x4 acc[4][8];
    #pragma unroll
    for (int mi = 0; mi < 4; ++mi)
        #pragma unroll
        for (int ni = 0; ni < 8; ++ni)
            acc[mi][ni] = (f32x4){0.f, 0.f, 0.f, 0.f};

    #pragma unroll
    for (int ks = 0; ks < 4; ++ks) {
        bf16x8 bfr[8];
        #pragma unroll
        for (int ni = 0; ni < 8; ++ni)
            bfr[ni] = *reinterpret_cast<const bf16x8*>(
                Bp + (size_t)(((nbb + ni) * 4 + ks) * 64 + lane) * 8);
        bf16x8 afr[4];
        #pragma unroll
        for (int mi = 0; mi < 4; ++mi) {
            const int row = mh * 64 + mi * 16 + l15;
            const int off = row * 256 + ((ks * 64 + lg * 16) ^ ((row & 7) << 4));
            afr[mi] = *reinterpret_cast<const bf16x8*>((const char*)Asw + off);
        }
        #pragma unroll
        for (int mi = 0; mi < 4; ++mi)
            #pragma unroll
            for (int ni = 0; ni < 8; ++ni)
                acc[mi][ni] = __builtin_amdgcn_mfma_f32_16x16x32_bf16(
                    afr[mi], bfr[ni], acc[mi][ni], 0, 0, 0);
    }
    __syncthreads();

    // ---- pass 0: pool (cols 0-255) -> LDS, global store, fused scores ----
    if (wn < 2) {
        const int colbase = wn * 128;
        #pragma unroll
        for (int ni = 0; ni < 8; ++ni) {
            const int col = colbase + ni * 16 + l15;
            #pragma unroll
            for (int mi = 0; mi < 4; ++mi) {
                #pragma unroll
                for (int r = 0; r < 4; ++r) {
                    const int row = mh * 64 + mi * 16 + lg * 4 + r;
                    const int byte = row * 512 + ((col * 2) ^ ((row & 7) << 4));
                    *reinterpret_cast<unsigned short*>(smem + byte) =
                        f2b(acc[mi][ni][r]);
                }
            }
        }
    }
    __syncthreads();
    {
        unsigned short* dst = ga.pool[rsel];
        #pragma unroll
        for (int i = 0; i < 8; ++i) {
            const int idx = i * 512 + t;     // 0..4095 16B chunks
            const int row = idx >> 5;        // 32 chunks per 512B row
            const int c16 = idx & 31;
            const int byte = row * 512 + ((c16 * 16) ^ ((row & 7) << 4));
            u16x8 v = *reinterpret_cast<const u16x8*>(smem + byte);
            if (m0 + row < Nrows)
                *reinterpret_cast<u16x8*>(dst + (size_t)(m0 + row) * 256 + c16 * 8) = v;
        }
    }
    // fused head scores from the pool tile in LDS: 128 rows x 8 heads
    #pragma unroll
    for (int q = 0; q < 2; ++q) {
        const int task = q * 512 + t;        // 0..1023
        const int ro = task >> 3, kk = task & 7;
        float pl = 0.f, pr = 0.f;
        const float* __restrict__ wA = ga.wvA[rsel] + kk * 64;
        const float* __restrict__ wB = ga.wvB[rsel] + kk * 64 + 32;
        #pragma unroll
        for (int j2 = 0; j2 < 4; ++j2) {
            const int col = kk * 32 + j2 * 8;
            const int byte = ro * 512 + ((col * 2) ^ ((ro & 7) << 4));
            u16x8 u = *reinterpret_cast<const u16x8*>(smem + byte);
            #pragma unroll
            for (int e = 0; e < 8; ++e) {
                const float v = b2f(u[e]);
                pl = fmaf(v, wA[j2 * 8 + e], pl);
                pr = fmaf(v, wB[j2 * 8 + e], pr);
            }
        }
        if (m0 + ro < Nrows) {
            ga.elOut[rsel][(size_t)(m0 + ro) * 8 + kk] = pl;
            ga.erOut[rsel][(size_t)(m0 + ro) * 8 + kk] = pr;
        }
    }
    __syncthreads();

    // ---- pass 1: resid (cols 256-511, +bres) -> LDS, global store ----
    if (wn >= 2) {
        const int colbase = (wn & 1) * 128;
        #pragma unroll
        for (int ni = 0; ni < 8; ++ni) {
            const int col = colbase + ni * 16 + l15;
            const float bv = bres[col];
            #pragma unroll
            for (int mi = 0; mi < 4; ++mi) {
                #pragma unroll
                for (int r = 0; r < 4; ++r) {
                    const int row = mh * 64 + mi * 16 + lg * 4 + r;
                    const int byte = row * 512 + ((col * 2) ^ ((row & 7) << 4));
                    *reinterpret_cast<unsigned short*>(smem + byte) =
                        f2b(acc[mi][ni][r] + bv);
                }
            }
        }
    }
    __syncthreads();
    {
        unsigned short* dst = ga.resid[rsel];
        #pragma unroll
        for (int i = 0; i < 8; ++i) {
            const int idx = i * 512 + t;
            const int row = idx >> 5;
            const int c16 = idx & 31;
            const int byte = row * 512 + ((c16 * 16) ^ ((row & 7) << 4));
            u16x8 v = *reinterpret_cast<const u16x8*>(smem + byte);
            if (m0 + row < Nrows)
                *reinterpret_cast<u16x8*>(dst + (size_t)(m0 + row) * 256 + c16 * 8) = v;
        }
    }
}

// ---------------------------------------------------------------------------
// CSR build (batched over 4 relations via blockIdx.y)
// ---------------------------------------------------------------------------
struct EdgePtrs {
    const int* src[4];
    const int* dst[4];
    int E[4];
    int csrOff[4];
};

__global__ __launch_bounds__(256)
void hist_k(EdgePtrs ep, int* __restrict__ counts4, int N)
{
    const int r = blockIdx.y;
    const int e = blockIdx.x * 256 + threadIdx.x;
    if (e < ep.E[r]) atomicAdd(counts4 + (size_t)r * N + ep.dst[r][e], 1);
}

__global__ __launch_bounds__(256)
void blksum_k(const int* __restrict__ counts4, int* __restrict__ blksum4, int N)
{
    const int r = blockIdx.y;
    const int* c = counts4 + (size_t)r * N;
    const int base = blockIdx.x * 1024 + threadIdx.x;
    int s = 0;
    #pragma unroll
    for (int i = 0; i < 4; ++i) { int idx = base + i * 256; if (idx < N) s += c[idx]; }
    __shared__ int sd[256];
    sd[threadIdx.x] = s; __syncthreads();
    for (int off = 128; off > 0; off >>= 1) {
        if (threadIdx.x < off) sd[threadIdx.x] += sd[threadIdx.x + off];
        __syncthreads();
    }
    if (threadIdx.x == 0) blksum4[r * 1024 + blockIdx.x] = sd[0];
}

__global__ __launch_bounds__(1024)
void scanblk_k(int* __restrict__ blksum4, int nbx)
{
    const int r = blockIdx.x;
    const int t = threadIdx.x;
    __shared__ int sd[1024];
    int v = (t < nbx) ? blksum4[r * 1024 + t] : 0;
    sd[t] = v; __syncthreads();
    for (int off = 1; off < 1024; off <<= 1) {
        int u = (t >= off) ? sd[t - off] : 0;
        __syncthreads();
        sd[t] += u;
        __syncthreads();
    }
    if (t < nbx) blksum4[r * 1024 + t] = sd[t] - v;
}

__global__ __launch_bounds__(256)
void cursor_k(const int* __restrict__ counts4, const int* __restrict__ blkoff4,
              int* __restrict__ cursor4, int N)
{
    const int r = blockIdx.y;
    const int* c = counts4 + (size_t)r * N;
    int* cur = cursor4 + (size_t)r * N;
    const int t = threadIdx.x;
    const int base = blockIdx.x * 1024 + t * 4;
    const int c0 = (base + 0 < N) ? c[base + 0] : 0;
    const int c1 = (base + 1 < N) ? c[base + 1] : 0;
    const int c2 = (base + 2 < N) ? c[base + 2] : 0;
    const int c3 = (base + 3 < N) ? c[base + 3] : 0;
    const int tsum = c0 + c1 + c2 + c3;
    __shared__ int sd[256];
    sd[t] = tsum; __syncthreads();
    for (int off = 1; off < 256; off <<= 1) {
        int u = (t >= off) ? sd[t - off] : 0;
        __syncthreads();
        sd[t] += u;
        __syncthreads();
    }
    int excl = sd[t] - tsum + blkoff4[r * 1024 + blockIdx.x];
    if (base + 0 < N) cur[base + 0] = excl;
    if (base + 1 < N) cur[base + 1] = excl + c0;
    if (base + 2 < N) cur[base + 2] = excl + c0 + c1;
    if (base + 3 < N) cur[base + 3] = excl + c0 + c1 + c2;
}

__global__ __launch_bounds__(256)
void scatter_k(EdgePtrs ep, int* __restrict__ cursor4, int* __restrict__ csr_src, int N)
{
    const int r = blockIdx.y;
    const int e = blockIdx.x * 256 + threadIdx.x;
    if (e < ep.E[r]) {
        const int d = ep.dst[r][e];
        const int pos = atomicAdd(cursor4 + (size_t)r * N + d, 1);
        csr_src[ep.csrOff[r] + pos] = ep.src[r][e];
    }
}

// ---------------------------------------------------------------------------
// Fused per-node kernel. One wave per node. Two edges per loop iteration:
// half-wave h processes edge 2i+h with 8 elems/lane (u16x8), cross-half
// shfl_xor(32) merges. el/er are pre-scaled by LOG2E -> single v_exp_f32.
// ---------------------------------------------------------------------------
struct NodeArgs {
    const int* csr[4];
    const int* cursor[4];
    const int* counts[4];
    const float* el[4];
    const float* er[4];
    const unsigned short* pool[4];
    const unsigned short* resid[4];
};

__global__ __launch_bounds__(256)
void node_k(NodeArgs na,
            const float* __restrict__ attn_ui, const float* __restrict__ attn_ii,
            const float* __restrict__ attn_iir,
            const float* __restrict__ a_user, const float* __restrict__ a_item,
            float* __restrict__ out, int Nrows)
{
    const int tid = threadIdx.x;
    const int lane = tid & 63;
    const int n = blockIdx.x * 4 + (tid >> 6);
    if (n >= Nrows) return;
    const int h = lane >> 5;          // edge parity within wave
    const int c = lane & 31;          // covers elems c*8 .. c*8+7; head k = c>>2
    const int k = c >> 2;

    const float si = 1.f / (1.f + __expf(-a_item[0])), osi = 1.f - si;
    const float su = 1.f / (1.f + __expf(-a_user[0])), osu = 1.f - su;

    float f[4][8];
    #pragma unroll
    for (int r = 0; r < 4; ++r) {
        const int deg = na.counts[r][n];
        const int end = na.cursor[r][n];
        const int start = end - deg;
        const float erk = na.er[r][(size_t)n * 8 + k];
        const int* __restrict__ csr = na.csr[r];
        const float* __restrict__ elr = na.el[r];
        const unsigned short* __restrict__ fs = na.pool[r];
        float s = 0.f;
        float a[8] = {0.f, 0.f, 0.f, 0.f, 0.f, 0.f, 0.f, 0.f};
        const int iters = (deg + 1) >> 1;
        for (int i = 0; i < iters; ++i) {
            const int idx = 2 * i + h;
            const bool valid = idx < deg;
            const int sidx = csr[start + (valid ? idx : 0)];
            const float x = elr[(size_t)sidx * 8 + k] + erk;     // already *LOG2E
            float e = __builtin_amdgcn_exp2f(fmaxf(x, NEG_SLOPE * x));
            e = valid ? e : 0.f;
            s += e;
            u16x8 u = *reinterpret_cast<const u16x8*>(fs + (size_t)sidx * 256 + c * 8);
            #pragma unroll
            for (int j = 0; j < 8; ++j) a[j] = fmaf(b2f(u[j]), e, a[j]);
        }
        s += __shfl_xor(s, 32);
        #pragma unroll
        for (int j = 0; j < 8; ++j) a[j] += __shfl_xor(a[j], 32);
        const float inv = (deg > 0) ? 1.f / s : 0.f;
        // gated residual immediately (keeps register pressure low)
        u16x8 R = *reinterpret_cast<const u16x8*>(na.resid[r] + (size_t)n * 256 + c * 8);
        const float sg = (r == 1) ? su : si;
        const float og = (r == 1) ? osu : osi;
        #pragma unroll
        for (int j = 0; j < 8; ++j)
            f[r][j] = sg * fmaxf(a[j] * inv, 0.f) + og * b2f(R[j]);
    }

    // cross-relation attention over f[0] (h_ui), f[2] (h_ii), f[3] (h_iir)
    float w[3][8];
    {
        const float* ap0 = attn_ui + c * 8;
        const float* ap1 = attn_ii + c * 8;
        const float* ap2 = attn_iir + c * 8;
        float4 l0 = *reinterpret_cast<const float4*>(ap0);
        float4 h0 = *reinterpret_cast<const float4*>(ap0 + 4);
        float4 l1 = *reinterpret_cast<const float4*>(ap1);
        float4 h1 = *reinterpret_cast<const float4*>(ap1 + 4);
        float4 l2 = *reinterpret_cast<const float4*>(ap2);
        float4 h2 = *reinterpret_cast<const float4*>(ap2 + 4);
        w[0][0]=l0.x; w[0][1]=l0.y; w[0][2]=l0.z; w[0][3]=l0.w;
        w[0][4]=h0.x; w[0][5]=h0.y; w[0][6]=h0.z; w[0][7]=h0.w;
        w[1][0]=l1.x; w[1][1]=l1.y; w[1][2]=l1.z; w[1][3]=l1.w;
        w[1][4]=h1.x; w[1][5]=h1.y; w[1][6]=h1.z; w[1][7]=h1.w;
        w[2][0]=l2.x; w[2][1]=l2.y; w[2][2]=l2.z; w[2][3]=l2.w;
        w[2][4]=h2.x; w[2][5]=h2.y; w[2][6]=h2.z; w[2][7]=h2.w;
    }
    float p[3][3];
    #pragma unroll
    for (int x = 0; x < 3; ++x) {
        p[x][0] = 0.f; p[x][1] = 0.f; p[x][2] = 0.f;
        #pragma unroll
        for (int j = 0; j < 8; ++j) {
            p[x][0] = fmaf(w[x][j], f[0][j], p[x][0]);
            p[x][1] = fmaf(w[x][j], f[2][j], p[x][1]);
            p[x][2] = fmaf(w[x][j], f[3][j], p[x][2]);
        }
        #pragma unroll
        for (int rr = 0; rr < 3; ++rr) {
            p[x][rr] += __shfl_xor(p[x][rr], 1);
            p[x][rr] += __shfl_xor(p[x][rr], 2);
        }
    }

    const size_t NK = (size_t)Nrows * 256;
    const size_t ob = (size_t)n * 256 + c * 8;
    if (h == 0) {
        const size_t xoff[3] = {0, 2 * NK, 3 * NK};
        #pragma unroll
        for (int x = 0; x < 3; ++x) {
            float a0 = lrelu(p[x][0]), a1 = lrelu(p[x][1]), a2 = lrelu(p[x][2]);
            float mx = fmaxf(a0, fmaxf(a1, a2));
            float e0 = __expf(a0 - mx), e1 = __expf(a1 - mx), e2 = __expf(a2 - mx);
            float inv = 1.f / (e0 + e1 + e2);
            e0 *= inv; e1 *= inv; e2 *= inv;
            float rv[8];
            #pragma unroll
            for (int j = 0; j < 8; ++j)
                rv[j] = e0 * f[0][j] + e1 * f[2][j] + e2 * f[3][j];
            *reinterpret_cast<float4*>(out + xoff[x] + ob) =
                make_float4(rv[0], rv[1], rv[2], rv[3]);
            *reinterpret_cast<float4*>(out + xoff[x] + ob + 4) =
                make_float4(rv[4], rv[5], rv[6], rv[7]);
        }
        *reinterpret_cast<float4*>(out + NK + ob) =
            make_float4(f[1][0], f[1][1], f[1][2], f[1][3]);
        *reinterpret_cast<float4*>(out + NK + ob + 4) =
            make_float4(f[1][4], f[1][5], f[1][6], f[1][7]);
    }
}

// ---------------------------------------------------------------------------
// Relation-level tiny matvecs. wvec is pre-scaled by LOG2E (only consumed by
// the el/er score path); ro (relation update output) is NOT scaled.
// ---------------------------------------------------------------------------
struct RelPtrs {
    const float* rf[4];
    const float* Wrel[4];
    const float* Wupd[4];
    const float* bupd[4];
};

__global__ __launch_bounds__(512)
void rel_k(RelPtrs P, float* __restrict__ wvec, float* __restrict__ ro)
{
    const int r = blockIdx.x;
    const int t = threadIdx.x;
    __shared__ float rfs[64];
    if (t < 64) rfs[t] = P.rf[r][t];
    __syncthreads();
    {
        const float* Wc = P.Wrel[r];
        float acc = 0.f;
        #pragma unroll 8
        for (int i = 0; i < 64; ++i) acc = fmaf(rfs[i], Wc[(size_t)i * 512 + t], acc);
        wvec[(size_t)r * 512 + t] = acc * LOG2E;
    }
    if (t < 256) {
        const float* Wc = P.Wupd[r];
        float acc = P.bupd[r][t];
        #pragma unroll 8
        for (int i = 0; i < 64; ++i) acc = fmaf(rfs[i], Wc[(size_t)i * 256 + t], acc);
        ro[(size_t)r * 256 + t] = acc;
    }
}

// ---------------------------------------------------------------------------
extern "C" void kernel_launch(void* const* d_in, const int* in_sizes, int n_in,
                              void* d_out, int out_size, void* d_ws, size_t ws_size,
                              hipStream_t stream)
{
    (void)n_in; (void)out_size; (void)ws_size;
    const float* feat_ui  = (const float*)d_in[0];
    const float* feat_iu  = (const float*)d_in[1];
    const float* feat_ii  = (const float*)d_in[2];
    const float* feat_iir = (const float*)d_in[3];
    const float* W_user   = (const float*)d_in[8];
    const float* W_item   = (const float*)d_in[9];
    const float* Wres_user = (const float*)d_in[18];
    const float* bres_user = (const float*)d_in[19];
    const float* Wres_item = (const float*)d_in[20];
    const float* bres_item = (const float*)d_in[21];
    const float* a_user = (const float*)d_in[22];
    const float* a_item = (const float*)d_in[23];
    const int N = in_sizes[0] / 128;
    const int Es[4] = {in_sizes[32], in_sizes[34], in_sizes[36], in_sizes[38]};
    int maxE = 0;
    for (int r = 0; r < 4; ++r) maxE = Es[r] > maxE ? Es[r] : maxE;

    const size_t NP = (size_t)N * 256;
    const size_t N8 = (size_t)N * 8;

    unsigned short* us = (unsigned short*)d_ws;
    unsigned short* pool[4];   // P0=fiu@Wu, P1=fui@Wi, P2=fiir@Wi, P3=fii@Wi
    unsigned short* resid[4];  // by relation: 0:h_ui 1:h_iu 2:h_ii 3:h_iir
    for (int r = 0; r < 4; ++r) pool[r]  = us + (size_t)r * NP;
    for (int r = 0; r < 4; ++r) resid[r] = us + (size_t)(4 + r) * NP;
    unsigned short* Bp_user = us + 8 * NP;            // [W_user | Wres_user] frags
    unsigned short* Bp_item = Bp_user + 65536;        // [W_item | Wres_item] frags
    float* fl = (float*)(Bp_item + 65536);
    float *el[4], *er[4];
    for (int r = 0; r < 4; ++r) { el[r] = fl + (size_t)(2 * r) * N8; er[r] = fl + (size_t)(2 * r + 1) * N8; }
    float* wvec = fl + 8 * N8;                        // 4 x 512
    int* counts4 = (int*)(wvec + 4 * 512);
    int* cursor4 = counts4 + 4 * (size_t)N;
    int* blksum4 = cursor4 + 4 * (size_t)N;
    int* csr_src = blksum4 + 4 * 1024;
    float* out = (float*)d_out;

    EdgePtrs ep;
    {
        int off = 0;
        const int si[4] = {32, 34, 36, 38};
        for (int r = 0; r < 4; ++r) {
            ep.src[r] = (const int*)d_in[si[r]];
            ep.dst[r] = (const int*)d_in[si[r] + 1];
            ep.E[r] = Es[r];
            ep.csrOff[r] = off;
            off += Es[r];
        }
    }

    (void)hipMemsetAsync(counts4, 0, 4 * (size_t)N * sizeof(int), stream);

    RelPtrs rp;
    rp.rf[0]   = (const float*)d_in[4];  rp.rf[1]   = (const float*)d_in[5];
    rp.rf[2]   = (const float*)d_in[6];  rp.rf[3]   = (const float*)d_in[7];
    rp.Wrel[0] = (const float*)d_in[10]; rp.Wrel[1] = (const float*)d_in[11];
    rp.Wrel[2] = (const float*)d_in[12]; rp.Wrel[3] = (const float*)d_in[13];
    rp.Wupd[0] = (const float*)d_in[24]; rp.Wupd[1] = (const float*)d_in[26];
    rp.Wupd[2] = (const float*)d_in[28]; rp.Wupd[3] = (const float*)d_in[30];
    rp.bupd[0] = (const float*)d_in[25]; rp.bupd[1] = (const float*)d_in[27];
    rp.bupd[2] = (const float*)d_in[29]; rp.bupd[3] = (const float*)d_in[31];
    rel_k<<<dim3(4), dim3(512), 0, stream>>>(rp, wvec, out + 4 * NP);

    PackArgs pa;
    pa.W1[0] = W_user; pa.W2[0] = Wres_user; pa.Bp[0] = Bp_user;
    pa.W1[1] = W_item; pa.W2[1] = Wres_item; pa.Bp[1] = Bp_item;
    pack_b_k<<<dim3(32, 2), 256, 0, stream>>>(pa);

    // CSR build
    const int geb = (maxE + 255) / 256;
    const int nbx = (N + 1023) / 1024;
    hist_k<<<dim3(geb, 4), 256, 0, stream>>>(ep, counts4, N);
    blksum_k<<<dim3(nbx, 4), 256, 0, stream>>>(counts4, blksum4, N);
    scanblk_k<<<dim3(4), 1024, 0, stream>>>(blksum4, nbx);
    cursor_k<<<dim3(nbx, 4), 256, 0, stream>>>(counts4, blksum4, cursor4, N);
    scatter_k<<<dim3(geb, 4), 256, 0, stream>>>(ep, cursor4, csr_src, N);

    // fused pool+residual GEMMs with fused head scores, all 4 in one dispatch
    const int pair[4] = {1, 0, 3, 2};
    GemmArgs ga;
    ga.A[0] = feat_iu;  ga.Bp[0] = Bp_user; ga.bres[0] = bres_user; ga.pool[0] = pool[0]; ga.resid[0] = resid[1];
    ga.A[1] = feat_ui;  ga.Bp[1] = Bp_item; ga.bres[1] = bres_item; ga.pool[1] = pool[1]; ga.resid[1] = resid[0];
    ga.A[2] = feat_iir; ga.Bp[2] = Bp_item; ga.bres[2] = bres_item; ga.pool[2] = pool[2]; ga.resid[2] = resid[3];
    ga.A[3] = feat_ii;  ga.Bp[3] = Bp_item; ga.bres[3] = bres_item; ga.pool[3] = pool[3]; ga.resid[3] = resid[2];
    for (int r = 0; r < 4; ++r) {
        ga.wvA[r]   = wvec + (size_t)r * 512;
        ga.wvB[r]   = wvec + (size_t)pair[r] * 512;
        ga.elOut[r] = el[r];
        ga.erOut[r] = er[pair[r]];
    }
    const int gb = (N + 127) / 128;
    mfma_gemm_k<<<dim3(gb, 4), 512, 0, stream>>>(ga, N);

    // fused aggregation + gated residual + cross-relation fusion
    NodeArgs na;
    for (int r = 0; r < 4; ++r) {
        na.csr[r]    = csr_src + ep.csrOff[r];
        na.cursor[r] = cursor4 + (size_t)r * N;
        na.counts[r] = counts4 + (size_t)r * N;
        na.el[r]     = el[r];
        na.er[r]     = er[r];
        na.pool[r]   = pool[r];
        na.resid[r]  = resid[r];
    }
    const int nb4 = (N + 3) / 4;
    node_k<<<nb4, 256, 0, stream>>>(na,
                                    (const float*)d_in[14], (const float*)d_in[16],
                                    (const float*)d_in[17],
                                    a_user, a_item, out, N);
}

// Round 7
// 688.464 us; speedup vs baseline: 1.2705x; 1.2705x over previous
//
#include <hip/hip_runtime.h>
#include <hip/hip_bf16.h>
#include <math.h>

#define NEG_SLOPE 0.2f
#define LOG2E 1.4426950408889634f

using bf16x8 = __attribute__((ext_vector_type(8))) short;
using f32x4  = __attribute__((ext_vector_type(4))) float;
using u16x8  = __attribute__((ext_vector_type(8))) unsigned short;
using u16x4  = __attribute__((ext_vector_type(4))) unsigned short;

__device__ __forceinline__ float lrelu(float x) { return x > 0.f ? x : NEG_SLOPE * x; }
__device__ __forceinline__ float dot4(float4 a, float4 b) {
    return a.x * b.x + a.y * b.y + a.z * b.z + a.w * b.w;
}
__device__ __forceinline__ unsigned short f2b(float x) {
    union { float f; unsigned u; } v; v.f = x;
    unsigned r = v.u + 0x7fff + ((v.u >> 16) & 1);
    return (unsigned short)(r >> 16);
}
__device__ __forceinline__ float b2f(unsigned short b) {
    union { unsigned u; float f; } v; v.u = ((unsigned)b) << 16;
    return v.f;
}
__device__ __forceinline__ float4 load4b(const unsigned short* p) {
    u16x4 u = *reinterpret_cast<const u16x4*>(p);
    return make_float4(b2f(u[0]), b2f(u[1]), b2f(u[2]), b2f(u[3]));
}

// ---------------------------------------------------------------------------
// Pack Wcat = [W1 | W2] (each 128x256 fp32, k-major) into MFMA B-fragment
// linear order, bf16. Batched: blockIdx.y selects the weight pair.
// ---------------------------------------------------------------------------
struct PackArgs {
    const float* W1[2];
    const float* W2[2];
    unsigned short* Bp[2];
};

__global__ __launch_bounds__(256)
void pack_b_k(PackArgs pa)
{
    const int p = blockIdx.y;
    const int gid = blockIdx.x * 256 + threadIdx.x;  // 0..8191
    const int lane = gid & 63;
    const int grp = gid >> 6;          // 0..127
    const int ks = grp & 3;
    const int nb = grp >> 2;           // 0..31
    const int n = nb * 16 + (lane & 15);
    const int k0 = ks * 32 + (lane >> 4) * 8;
    const float* Wsrc = (n < 256) ? (pa.W1[p] + n) : (pa.W2[p] + (n - 256));
    u16x8 u;
    #pragma unroll
    for (int e = 0; e < 8; ++e) u[e] = f2b(Wsrc[(size_t)(k0 + e) * 256]);
    *reinterpret_cast<u16x8*>(pa.Bp[p] + (size_t)gid * 8) = u;
}

// ---------------------------------------------------------------------------
// MFMA GEMM, batched over 4 tuples via blockIdx.y.
// A[N x 128] fp32 @ Wcat[128 x 512] bf16-frags -> pool (cols 0-255, bf16),
// resid (cols 256-511, +bres, bf16). Fused head scores (el/er) computed from
// the pool tile while it sits in LDS. el/er pre-scaled by LOG2E (rel_k).
// ---------------------------------------------------------------------------
struct GemmArgs {
    const float* A[4];
    const unsigned short* Bp[4];
    const float* bres[4];
    unsigned short* pool[4];
    unsigned short* resid[4];
    const float* wvA[4];
    const float* wvB[4];
    float* elOut[4];
    float* erOut[4];
};

__global__ __launch_bounds__(512)
void mfma_gemm_k(GemmArgs ga, int Nrows)
{
    __shared__ __align__(16) char smem[65536];
    unsigned short* Asw = (unsigned short*)smem;
    const int rsel = blockIdx.y;
    const float* __restrict__ A = ga.A[rsel];
    const unsigned short* __restrict__ Bp = ga.Bp[rsel];
    const float* __restrict__ bres = ga.bres[rsel];
    const int t = threadIdx.x;
    const int m0 = blockIdx.x * 128;

    // stage A: 128 rows x 128 k, fp32 -> bf16, XOR-swizzled (first 32 KB)
    #pragma unroll
    for (int i = 0; i < 4; ++i) {
        const int idx = i * 512 + t;        // 0..2047
        const int row = idx >> 4;           // 0..127
        const int cg  = idx & 15;           // 16B chunk (8 bf16)
        float4 a0 = make_float4(0.f, 0.f, 0.f, 0.f), a1 = a0;
        if (m0 + row < Nrows) {
            const float* p = A + (size_t)(m0 + row) * 128 + cg * 8;
            a0 = *reinterpret_cast<const float4*>(p);
            a1 = *reinterpret_cast<const float4*>(p + 4);
        }
        u16x8 u;
        u[0] = f2b(a0.x); u[1] = f2b(a0.y); u[2] = f2b(a0.z); u[3] = f2b(a0.w);
        u[4] = f2b(a1.x); u[5] = f2b(a1.y); u[6] = f2b(a1.z); u[7] = f2b(a1.w);
        const int off = row * 256 + ((cg * 16) ^ ((row & 7) << 4));
        *reinterpret_cast<u16x8*>((char*)Asw + off) = u;
    }
    __syncthreads();

    const int wv = t >> 6, lane = t & 63;
    const int mh = wv >> 2;          // row half (0/1)
    const int wn = wv & 3;           // 128-col slice
    const int l15 = lane & 15, lg = lane >> 4;
    const int nbb = wn * 8;

    f32x4 acc[4][8];
    #pragma unroll
    for (int mi = 0; mi < 4; ++mi)
        #pragma unroll
        for (int ni = 0; ni < 8; ++ni)
            acc[mi][ni] = (f32x4){0.f, 0.f, 0.f, 0.f};

    #pragma unroll
    for (int ks = 0; ks < 4; ++ks) {
        bf16x8 bfr[8];
        #pragma unroll
        for (int ni = 0; ni < 8; ++ni)
            bfr[ni] = *reinterpret_cast<const bf16x8*>(
                Bp + (size_t)(((nbb + ni) * 4 + ks) * 64 + lane) * 8);
        bf16x8 afr[4];
        #pragma unroll
        for (int mi = 0; mi < 4; ++mi) {
            const int row = mh * 64 + mi * 16 + l15;
            const int off = row * 256 + ((ks * 64 + lg * 16) ^ ((row & 7) << 4));
            afr[mi] = *reinterpret_cast<const bf16x8*>((const char*)Asw + off);
        }
        #pragma unroll
        for (int mi = 0; mi < 4; ++mi)
            #pragma unroll
            for (int ni = 0; ni < 8; ++ni)
                acc[mi][ni] = __builtin_amdgcn_mfma_f32_16x16x32_bf16(
                    afr[mi], bfr[ni], acc[mi][ni], 0, 0, 0);
    }
    __syncthreads();

    // ---- pass 0: pool (cols 0-255) -> LDS, global store, fused scores ----
    if (wn < 2) {
        const int colbase = wn * 128;
        #pragma unroll
        for (int ni = 0; ni < 8; ++ni) {
            const int col = colbase + ni * 16 + l15;
            #pragma unroll
            for (int mi = 0; mi < 4; ++mi) {
                #pragma unroll
                for (int r = 0; r < 4; ++r) {
                    const int row = mh * 64 + mi * 16 + lg * 4 + r;
                    const int byte = row * 512 + ((col * 2) ^ ((row & 7) << 4));
                    *reinterpret_cast<unsigned short*>(smem + byte) =
                        f2b(acc[mi][ni][r]);
                }
            }
        }
    }
    __syncthreads();
    {
        unsigned short* dst = ga.pool[rsel];
        #pragma unroll
        for (int i = 0; i < 8; ++i) {
            const int idx = i * 512 + t;     // 0..4095 16B chunks
            const int row = idx >> 5;        // 32 chunks per 512B row
            const int c16 = idx & 31;
            const int byte = row * 512 + ((c16 * 16) ^ ((row & 7) << 4));
            u16x8 v = *reinterpret_cast<const u16x8*>(smem + byte);
            if (m0 + row < Nrows)
                *reinterpret_cast<u16x8*>(dst + (size_t)(m0 + row) * 256 + c16 * 8) = v;
        }
    }
    // fused head scores from the pool tile in LDS: 128 rows x 8 heads
    #pragma unroll
    for (int q = 0; q < 2; ++q) {
        const int task = q * 512 + t;        // 0..1023
        const int ro = task >> 3, kk = task & 7;
        float pl = 0.f, pr = 0.f;
        const float* __restrict__ wA = ga.wvA[rsel] + kk * 64;
        const float* __restrict__ wB = ga.wvB[rsel] + kk * 64 + 32;
        #pragma unroll
        for (int j2 = 0; j2 < 4; ++j2) {
            const int col = kk * 32 + j2 * 8;
            const int byte = ro * 512 + ((col * 2) ^ ((ro & 7) << 4));
            u16x8 u = *reinterpret_cast<const u16x8*>(smem + byte);
            #pragma unroll
            for (int e = 0; e < 8; ++e) {
                const float v = b2f(u[e]);
                pl = fmaf(v, wA[j2 * 8 + e], pl);
                pr = fmaf(v, wB[j2 * 8 + e], pr);
            }
        }
        if (m0 + ro < Nrows) {
            ga.elOut[rsel][(size_t)(m0 + ro) * 8 + kk] = pl;
            ga.erOut[rsel][(size_t)(m0 + ro) * 8 + kk] = pr;
        }
    }
    __syncthreads();

    // ---- pass 1: resid (cols 256-511, +bres) -> LDS, global store ----
    if (wn >= 2) {
        const int colbase = (wn & 1) * 128;
        #pragma unroll
        for (int ni = 0; ni < 8; ++ni) {
            const int col = colbase + ni * 16 + l15;
            const float bv = bres[col];
            #pragma unroll
            for (int mi = 0; mi < 4; ++mi) {
                #pragma unroll
                for (int r = 0; r < 4; ++r) {
                    const int row = mh * 64 + mi * 16 + lg * 4 + r;
                    const int byte = row * 512 + ((col * 2) ^ ((row & 7) << 4));
                    *reinterpret_cast<unsigned short*>(smem + byte) =
                        f2b(acc[mi][ni][r] + bv);
                }
            }
        }
    }
    __syncthreads();
    {
        unsigned short* dst = ga.resid[rsel];
        #pragma unroll
        for (int i = 0; i < 8; ++i) {
            const int idx = i * 512 + t;
            const int row = idx >> 5;
            const int c16 = idx & 31;
            const int byte = row * 512 + ((c16 * 16) ^ ((row & 7) << 4));
            u16x8 v = *reinterpret_cast<const u16x8*>(smem + byte);
            if (m0 + row < Nrows)
                *reinterpret_cast<u16x8*>(dst + (size_t)(m0 + row) * 256 + c16 * 8) = v;
        }
    }
}

// ---------------------------------------------------------------------------
// CSR build (batched over 4 relations via blockIdx.y)
// ---------------------------------------------------------------------------
struct EdgePtrs {
    const int* src[4];
    const int* dst[4];
    int E[4];
    int csrOff[4];
};

__global__ __launch_bounds__(256)
void hist_k(EdgePtrs ep, int* __restrict__ counts4, int N)
{
    const int r = blockIdx.y;
    const int e = blockIdx.x * 256 + threadIdx.x;
    if (e < ep.E[r]) atomicAdd(counts4 + (size_t)r * N + ep.dst[r][e], 1);
}

__global__ __launch_bounds__(256)
void blksum_k(const int* __restrict__ counts4, int* __restrict__ blksum4, int N)
{
    const int r = blockIdx.y;
    const int* c = counts4 + (size_t)r * N;
    const int base = blockIdx.x * 1024 + threadIdx.x;
    int s = 0;
    #pragma unroll
    for (int i = 0; i < 4; ++i) { int idx = base + i * 256; if (idx < N) s += c[idx]; }
    __shared__ int sd[256];
    sd[threadIdx.x] = s; __syncthreads();
    for (int off = 128; off > 0; off >>= 1) {
        if (threadIdx.x < off) sd[threadIdx.x] += sd[threadIdx.x + off];
        __syncthreads();
    }
    if (threadIdx.x == 0) blksum4[r * 1024 + blockIdx.x] = sd[0];
}

__global__ __launch_bounds__(1024)
void scanblk_k(int* __restrict__ blksum4, int nbx)
{
    const int r = blockIdx.x;
    const int t = threadIdx.x;
    __shared__ int sd[1024];
    int v = (t < nbx) ? blksum4[r * 1024 + t] : 0;
    sd[t] = v; __syncthreads();
    for (int off = 1; off < 1024; off <<= 1) {
        int u = (t >= off) ? sd[t - off] : 0;
        __syncthreads();
        sd[t] += u;
        __syncthreads();
    }
    if (t < nbx) blksum4[r * 1024 + t] = sd[t] - v;
}

__global__ __launch_bounds__(256)
void cursor_k(const int* __restrict__ counts4, const int* __restrict__ blkoff4,
              int* __restrict__ cursor4, int N)
{
    const int r = blockIdx.y;
    const int* c = counts4 + (size_t)r * N;
    int* cur = cursor4 + (size_t)r * N;
    const int t = threadIdx.x;
    const int base = blockIdx.x * 1024 + t * 4;
    const int c0 = (base + 0 < N) ? c[base + 0] : 0;
    const int c1 = (base + 1 < N) ? c[base + 1] : 0;
    const int c2 = (base + 2 < N) ? c[base + 2] : 0;
    const int c3 = (base + 3 < N) ? c[base + 3] : 0;
    const int tsum = c0 + c1 + c2 + c3;
    __shared__ int sd[256];
    sd[t] = tsum; __syncthreads();
    for (int off = 1; off < 256; off <<= 1) {
        int u = (t >= off) ? sd[t - off] : 0;
        __syncthreads();
        sd[t] += u;
        __syncthreads();
    }
    int excl = sd[t] - tsum + blkoff4[r * 1024 + blockIdx.x];
    if (base + 0 < N) cur[base + 0] = excl;
    if (base + 1 < N) cur[base + 1] = excl + c0;
    if (base + 2 < N) cur[base + 2] = excl + c0 + c1;
    if (base + 3 < N) cur[base + 3] = excl + c0 + c1 + c2;
}

__global__ __launch_bounds__(256)
void scatter_k(EdgePtrs ep, int* __restrict__ cursor4, int* __restrict__ csr_src, int N)
{
    const int r = blockIdx.y;
    const int e = blockIdx.x * 256 + threadIdx.x;
    if (e < ep.E[r]) {
        const int d = ep.dst[r][e];
        const int pos = atomicAdd(cursor4 + (size_t)r * N + d, 1);
        csr_src[ep.csrOff[r] + pos] = ep.src[r][e];
    }
}

// ---------------------------------------------------------------------------
// Fused per-node kernel. One wave per node, 4 elems/lane (R5 structure).
// Edge loop runs in 4-edge chunks: all csr loads, then all el loads, then all
// pool loads issued as independent requests (MLP ~8-10/wave) before consuming.
// el/er pre-scaled by LOG2E -> single v_exp_f32 per edge.
// ---------------------------------------------------------------------------
struct NodeArgs {
    const int* csr[4];
    const int* cursor[4];
    const int* counts[4];
    const float* el[4];
    const float* er[4];
    const unsigned short* pool[4];
    const unsigned short* resid[4];
};

__global__ __launch_bounds__(256)
void node_k(NodeArgs na,
            const float* __restrict__ attn_ui, const float* __restrict__ attn_ii,
            const float* __restrict__ attn_iir,
            const float* __restrict__ a_user, const float* __restrict__ a_item,
            float* __restrict__ out, int Nrows)
{
    const int lane = threadIdx.x & 63;
    const int n = blockIdx.x * 4 + (threadIdx.x >> 6);
    if (n >= Nrows) return;
    const int k = lane >> 3;

    // hoist all per-node metadata loads (12 independent requests)
    int deg[4], endv[4];
    float erk[4];
    #pragma unroll
    for (int r = 0; r < 4; ++r) {
        deg[r]  = na.counts[r][n];
        endv[r] = na.cursor[r][n];
        erk[r]  = na.er[r][(size_t)n * 8 + k];
    }

    const float si = 1.f / (1.f + __expf(-a_item[0])), osi = 1.f - si;
    const float su = 1.f / (1.f + __expf(-a_user[0])), osu = 1.f - su;

    float4 fr[4];
    #pragma unroll
    for (int r = 0; r < 4; ++r) {
        const int d = deg[r];
        const int start = endv[r] - d;
        const int* __restrict__ csr = na.csr[r];
        const float* __restrict__ elr = na.el[r];
        const unsigned short* __restrict__ fs = na.pool[r];
        const float er_k = erk[r];
        float s = 0.f;
        float4 acc = make_float4(0.f, 0.f, 0.f, 0.f);
        for (int base = 0; base < d; base += 4) {
            const int m = d - base;            // valid edges this chunk
            int sidx[4];
            #pragma unroll
            for (int u = 0; u < 4; ++u)
                sidx[u] = csr[start + base + ((u < m) ? u : 0)];
            float ex[4];
            #pragma unroll
            for (int u = 0; u < 4; ++u) {
                const float x = elr[(size_t)sidx[u] * 8 + k] + er_k;  // *LOG2E
                const float e = __builtin_amdgcn_exp2f(fmaxf(x, NEG_SLOPE * x));
                ex[u] = (u < m) ? e : 0.f;
            }
            float4 pv[4];
            #pragma unroll
            for (int u = 0; u < 4; ++u)
                pv[u] = load4b(fs + (size_t)sidx[u] * 256 + lane * 4);
            #pragma unroll
            for (int u = 0; u < 4; ++u) {
                s += ex[u];
                acc.x = fmaf(pv[u].x, ex[u], acc.x);
                acc.y = fmaf(pv[u].y, ex[u], acc.y);
                acc.z = fmaf(pv[u].z, ex[u], acc.z);
                acc.w = fmaf(pv[u].w, ex[u], acc.w);
            }
        }
        const float inv = (d > 0) ? 1.f / s : 0.f;
        float4 R = load4b(na.resid[r] + (size_t)n * 256 + lane * 4);
        const float sg = (r == 1) ? su : si;
        const float og = (r == 1) ? osu : osi;
        fr[r].x = sg * fmaxf(acc.x * inv, 0.f) + og * R.x;
        fr[r].y = sg * fmaxf(acc.y * inv, 0.f) + og * R.y;
        fr[r].z = sg * fmaxf(acc.z * inv, 0.f) + og * R.z;
        fr[r].w = sg * fmaxf(acc.w * inv, 0.f) + og * R.w;
    }

    // cross-relation attention over fr[0] (h_ui), fr[2] (h_ii), fr[3] (h_iir)
    const float4 f0 = fr[0], f1 = fr[2], f2 = fr[3], fiu = fr[1];
    float4 w0 = *reinterpret_cast<const float4*>(attn_ui  + lane * 4);
    float4 w1 = *reinterpret_cast<const float4*>(attn_ii  + lane * 4);
    float4 w2 = *reinterpret_cast<const float4*>(attn_iir + lane * 4);

    float p[3][3];
    p[0][0] = dot4(w0, f0); p[0][1] = dot4(w0, f1); p[0][2] = dot4(w0, f2);
    p[1][0] = dot4(w1, f0); p[1][1] = dot4(w1, f1); p[1][2] = dot4(w1, f2);
    p[2][0] = dot4(w2, f0); p[2][1] = dot4(w2, f1); p[2][2] = dot4(w2, f2);
    #pragma unroll
    for (int x = 0; x < 3; ++x)
        #pragma unroll
        for (int r = 0; r < 3; ++r)
            #pragma unroll
            for (int m = 1; m < 8; m <<= 1)
                p[x][r] += __shfl_xor(p[x][r], m, 64);

    const size_t NK = (size_t)Nrows * 256;
    const size_t o = (size_t)n * 256 + lane * 4;
    const size_t xoff[3] = {0, 2 * NK, 3 * NK};
    #pragma unroll
    for (int x = 0; x < 3; ++x) {
        float a0 = lrelu(p[x][0]), a1 = lrelu(p[x][1]), a2 = lrelu(p[x][2]);
        float mx = fmaxf(a0, fmaxf(a1, a2));
        float e0 = __expf(a0 - mx), e1 = __expf(a1 - mx), e2 = __expf(a2 - mx);
        float inv = 1.f / (e0 + e1 + e2);
        e0 *= inv; e1 *= inv; e2 *= inv;
        float4 rr;
        rr.x = e0 * f0.x + e1 * f1.x + e2 * f2.x;
        rr.y = e0 * f0.y + e1 * f1.y + e2 * f2.y;
        rr.z = e0 * f0.z + e1 * f1.z + e2 * f2.z;
        rr.w = e0 * f0.w + e1 * f1.w + e2 * f2.w;
        *reinterpret_cast<float4*>(out + xoff[x] + o) = rr;
    }
    *reinterpret_cast<float4*>(out + NK + o) = fiu;
}

// ---------------------------------------------------------------------------
// Relation-level tiny matvecs. wvec pre-scaled by LOG2E (only feeds el/er);
// ro (relation update output) NOT scaled.
// ---------------------------------------------------------------------------
struct RelPtrs {
    const float* rf[4];
    const float* Wrel[4];
    const float* Wupd[4];
    const float* bupd[4];
};

__global__ __launch_bounds__(512)
void rel_k(RelPtrs P, float* __restrict__ wvec, float* __restrict__ ro)
{
    const int r = blockIdx.x;
    const int t = threadIdx.x;
    __shared__ float rfs[64];
    if (t < 64) rfs[t] = P.rf[r][t];
    __syncthreads();
    {
        const float* Wc = P.Wrel[r];
        float acc = 0.f;
        #pragma unroll 8
        for (int i = 0; i < 64; ++i) acc = fmaf(rfs[i], Wc[(size_t)i * 512 + t], acc);
        wvec[(size_t)r * 512 + t] = acc * LOG2E;
    }
    if (t < 256) {
        const float* Wc = P.Wupd[r];
        float acc = P.bupd[r][t];
        #pragma unroll 8
        for (int i = 0; i < 64; ++i) acc = fmaf(rfs[i], Wc[(size_t)i * 256 + t], acc);
        ro[(size_t)r * 256 + t] = acc;
    }
}

// ---------------------------------------------------------------------------
extern "C" void kernel_launch(void* const* d_in, const int* in_sizes, int n_in,
                              void* d_out, int out_size, void* d_ws, size_t ws_size,
                              hipStream_t stream)
{
    (void)n_in; (void)out_size; (void)ws_size;
    const float* feat_ui  = (const float*)d_in[0];
    const float* feat_iu  = (const float*)d_in[1];
    const float* feat_ii  = (const float*)d_in[2];
    const float* feat_iir = (const float*)d_in[3];
    const float* W_user   = (const float*)d_in[8];
    const float* W_item   = (const float*)d_in[9];
    const float* Wres_user = (const float*)d_in[18];
    const float* bres_user = (const float*)d_in[19];
    const float* Wres_item = (const float*)d_in[20];
    const float* bres_item = (const float*)d_in[21];
    const float* a_user = (const float*)d_in[22];
    const float* a_item = (const float*)d_in[23];
    const int N = in_sizes[0] / 128;
    const int Es[4] = {in_sizes[32], in_sizes[34], in_sizes[36], in_sizes[38]};
    int maxE = 0;
    for (int r = 0; r < 4; ++r) maxE = Es[r] > maxE ? Es[r] : maxE;

    const size_t NP = (size_t)N * 256;
    const size_t N8 = (size_t)N * 8;

    unsigned short* us = (unsigned short*)d_ws;
    unsigned short* pool[4];   // P0=fiu@Wu, P1=fui@Wi, P2=fiir@Wi, P3=fii@Wi
    unsigned short* resid[4];  // by relation: 0:h_ui 1:h_iu 2:h_ii 3:h_iir
    for (int r = 0; r < 4; ++r) pool[r]  = us + (size_t)r * NP;
    for (int r = 0; r < 4; ++r) resid[r] = us + (size_t)(4 + r) * NP;
    unsigned short* Bp_user = us + 8 * NP;            // [W_user | Wres_user] frags
    unsigned short* Bp_item = Bp_user + 65536;        // [W_item | Wres_item] frags
    float* fl = (float*)(Bp_item + 65536);
    float *el[4], *er[4];
    for (int r = 0; r < 4; ++r) { el[r] = fl + (size_t)(2 * r) * N8; er[r] = fl + (size_t)(2 * r + 1) * N8; }
    float* wvec = fl + 8 * N8;                        // 4 x 512
    int* counts4 = (int*)(wvec + 4 * 512);
    int* cursor4 = counts4 + 4 * (size_t)N;
    int* blksum4 = cursor4 + 4 * (size_t)N;
    int* csr_src = blksum4 + 4 * 1024;
    float* out = (float*)d_out;

    EdgePtrs ep;
    {
        int off = 0;
        const int si[4] = {32, 34, 36, 38};
        for (int r = 0; r < 4; ++r) {
            ep.src[r] = (const int*)d_in[si[r]];
            ep.dst[r] = (const int*)d_in[si[r] + 1];
            ep.E[r] = Es[r];
            ep.csrOff[r] = off;
            off += Es[r];
        }
    }

    (void)hipMemsetAsync(counts4, 0, 4 * (size_t)N * sizeof(int), stream);

    RelPtrs rp;
    rp.rf[0]   = (const float*)d_in[4];  rp.rf[1]   = (const float*)d_in[5];
    rp.rf[2]   = (const float*)d_in[6];  rp.rf[3]   = (const float*)d_in[7];
    rp.Wrel[0] = (const float*)d_in[10]; rp.Wrel[1] = (const float*)d_in[11];
    rp.Wrel[2] = (const float*)d_in[12]; rp.Wrel[3] = (const float*)d_in[13];
    rp.Wupd[0] = (const float*)d_in[24]; rp.Wupd[1] = (const float*)d_in[26];
    rp.Wupd[2] = (const float*)d_in[28]; rp.Wupd[3] = (const float*)d_in[30];
    rp.bupd[0] = (const float*)d_in[25]; rp.bupd[1] = (const float*)d_in[27];
    rp.bupd[2] = (const float*)d_in[29]; rp.bupd[3] = (const float*)d_in[31];
    rel_k<<<dim3(4), dim3(512), 0, stream>>>(rp, wvec, out + 4 * NP);

    PackArgs pa;
    pa.W1[0] = W_user; pa.W2[0] = Wres_user; pa.Bp[0] = Bp_user;
    pa.W1[1] = W_item; pa.W2[1] = Wres_item; pa.Bp[1] = Bp_item;
    pack_b_k<<<dim3(32, 2), 256, 0, stream>>>(pa);

    // CSR build
    const int geb = (maxE + 255) / 256;
    const int nbx = (N + 1023) / 1024;
    hist_k<<<dim3(geb, 4), 256, 0, stream>>>(ep, counts4, N);
    blksum_k<<<dim3(nbx, 4), 256, 0, stream>>>(counts4, blksum4, N);
    scanblk_k<<<dim3(4), 1024, 0, stream>>>(blksum4, nbx);
    cursor_k<<<dim3(nbx, 4), 256, 0, stream>>>(counts4, blksum4, cursor4, N);
    scatter_k<<<dim3(geb, 4), 256, 0, stream>>>(ep, cursor4, csr_src, N);

    // fused pool+residual GEMMs with fused head scores, all 4 in one dispatch
    const int pair[4] = {1, 0, 3, 2};
    GemmArgs ga;
    ga.A[0] = feat_iu;  ga.Bp[0] = Bp_user; ga.bres[0] = bres_user; ga.pool[0] = pool[0]; ga.resid[0] = resid[1];
    ga.A[1] = feat_ui;  ga.Bp[1] = Bp_item; ga.bres[1] = bres_item; ga.pool[1] = pool[1]; ga.resid[1] = resid[0];
    ga.A[2] = feat_iir; ga.Bp[2] = Bp_item; ga.bres[2] = bres_item; ga.pool[2] = pool[2]; ga.resid[2] = resid[3];
    ga.A[3] = feat_ii;  ga.Bp[3] = Bp_item; ga.bres[3] = bres_item; ga.pool[3] = pool[3]; ga.resid[3] = resid[2];
    for (int r = 0; r < 4; ++r) {
        ga.wvA[r]   = wvec + (size_t)r * 512;
        ga.wvB[r]   = wvec + (size_t)pair[r] * 512;
        ga.elOut[r] = el[r];
        ga.erOut[r] = er[pair[r]];
    }
    const int gb = (N + 127) / 128;
    mfma_gemm_k<<<dim3(gb, 4), 512, 0, stream>>>(ga, N);

    // fused aggregation + gated residual + cross-relation fusion
    NodeArgs na;
    for (int r = 0; r < 4; ++r) {
        na.csr[r]    = csr_src + ep.csrOff[r];
        na.cursor[r] = cursor4 + (size_t)r * N;
        na.counts[r] = counts4 + (size_t)r * N;
        na.el[r]     = el[r];
        na.er[r]     = er[r];
        na.pool[r]   = pool[r];
        na.resid[r]  = resid[r];
    }
    const int nb4 = (N + 3) / 4;
    node_k<<<nb4, 256, 0, stream>>>(na,
                                    (const float*)d_in[14], (const float*)d_in[16],
                                    (const float*)d_in[17],
                                    a_user, a_item, out, N);
}